// Round 3
// baseline (178.114 us; speedup 1.0000x reference)
//
#include <hip/hip_runtime.h>
#include <math.h>

#define HDIM 2048
#define WDIM 2048
#define NPIX (HDIM*WDIM)
#define OUTW 2038          /* valid conv output size: 2048-10 */

#define C1F 6.5025f        /* (0.01*255)^2 */
#define C2F 58.5225f       /* (0.03*255)^2 */

constexpr int TH   = 64, TW = 32;  // output tile
constexpr int IN_R = 80;           // input rows staged (5 MFMA row-blocks of 16)
constexpr int IQ_S = 72;           // f16 staging row stride (144 B = 36 dw == 4 banks ->
                                   //   8 consecutive rows start at banks 0,4,..,28: uniform)
constexpr int IQ_H = IN_R * IQ_S;  // 5760 f16 per image
constexpr int HT_R = 80;           // HT row stride: [arr][col][row], 160 B/col == 8 banks
constexpr int HT_A = 32 * HT_R;    // 2560 f16 per array
constexpr int NBLK = 8192;         // 64 x 32 x 4 blocks

struct GaussW { float g[11]; };

typedef _Float16 half8 __attribute__((ext_vector_type(8)));
typedef float    f32x4 __attribute__((ext_vector_type(4)));

// quant: bit-exact vs reference sequence. (clip(x)+1)*0.5 then *255 ==
// (clip(x)+1)*127.5 (the *0.5 is exact); trunc == floor for v >= 0.
__device__ __forceinline__ float quant_u8f(float x) {
    float c = __builtin_amdgcn_fmed3f(x, -1.0f, 1.0f);
    return truncf((c + 1.0f) * 127.5f);
}

__device__ __forceinline__ unsigned pk2(float a, float b) {
    return __builtin_bit_cast(unsigned, __builtin_amdgcn_cvt_pkrtz(a, b));
}

// ---------------------------------------------------------------------------
// Fused kernel, MFMA edition (round 10 resubmit: 25.8 KB LDS -> 6 blocks/CU).
//   Union buffer phases:
//     phase 1: Iq staging (2 x 11520 B) + Tg Gaussian table at tail (+23040 B)
//     phase 2: HT[5][col 32][row 80] f16 (25600 B) -- overwrites everything;
//              safe because gfrag + A-fragments are register-preloaded before
//              the barrier that precedes the first HT write.
//   stage A: load f32, pointwise stats on owned core, quantize -> f16 LDS
//   stage H: horizontal 11-tap conv as mfma_f32_16x16x32_f16 (A = data rows,
//            B = banded Gaussian T); D written transposed: HT[arr][col][row].
//   stage V: vertical conv as MFMA (A = same T fragment, B = HT col-major
//            rows, b128) + SSIM map on aligned C/D fragments.
// Channels: 0:l1 1:gxH 2:gyW 3:relu 4:sp 5:st 6:spp 7:stt 8:su8 9:ssim
// ---------------------------------------------------------------------------
__global__ __launch_bounds__(256, 6) void amsr2_fused(
        const float* __restrict__ pred, const float* __restrict__ targ,
        float* __restrict__ pr, GaussW gw)
{
    __shared__ alignas(16) _Float16 Ubuf[5 * HT_A];   // 12800 f16 = 25600 B
    __shared__ float sred[4][10];
    _Float16* Iq = Ubuf;                     // [0, 23040 B): 2 x 80 x 72 f16
    _Float16* Tg = Ubuf + 2 * IQ_H;          // [23040, 24064 B): 16 x 32 f16

    const int b  = blockIdx.z;
    const int r0 = blockIdx.y * TH;
    const int c0 = blockIdx.x * TW;
    const float* pb = pred + (size_t)b * NPIX;
    const float* tb = targ + (size_t)b * NPIX;
    const bool interior = (blockIdx.y < 31) && (blockIdx.x < 63);

    // ---- banded Gaussian table (threads 0..15; each owns its row) ----
    if (threadIdx.x < 16) {
        int n = threadIdx.x;
#pragma unroll
        for (int i = 0; i < 16; ++i) ((unsigned*)Tg)[n * 16 + i] = 0u;
#pragma unroll
        for (int j = 0; j < 11; ++j) Tg[n * 32 + n + j] = (_Float16)gw.g[j];
    }

    float s[9];
#pragma unroll
    for (int c = 0; c < 9; ++c) s[c] = 0.0f;

    // ---- stage A: 80 rows x 48 cols staged; core(512) + halo(256+192) ----
    if (interior) {
        // core items: 64 rows x 8 dword-groups (cols 0..31) -- fully unguarded
#pragma unroll
        for (int i = 0; i < 2; ++i) {
            int item = threadIdx.x + i * 256;
            int r = item >> 3, d = item & 7;
            const float* prow = pb + (size_t)(r0 + r) * WDIM + (c0 + d * 4);
            const float* trow = tb + (size_t)(r0 + r) * WDIM + (c0 + d * 4);
            float4 a4 = *(const float4*)prow;
            float4 b4 = *(const float4*)trow;
            float4 ad = *(const float4*)(prow + WDIM);
            float4 bd = *(const float4*)(trow + WDIM);
            float p5 = prow[4], t5 = trow[4];
            float pv[4] = {a4.x, a4.y, a4.z, a4.w};
            float tv[4] = {b4.x, b4.y, b4.z, b4.w};
            float pd[4] = {ad.x, ad.y, ad.z, ad.w};
            float td[4] = {bd.x, bd.y, bd.z, bd.w};
            float qp[4], qt[4];
#pragma unroll
            for (int k = 0; k < 4; ++k) { qp[k] = quant_u8f(pv[k]); qt[k] = quant_u8f(tv[k]); }
#pragma unroll
            for (int k = 0; k < 4; ++k) {
                float av = pv[k], bv = tv[k];
                float dd = av - bv;
                s[0] += fabsf(dd);
                s[3] += fmaxf(fabsf(av) - 1.0f, 0.0f);
                s[4] += av;  s[5] += bv;
                s[6] = fmaf(av, av, s[6]);
                s[7] = fmaf(bv, bv, s[7]);
                s[1] += fabsf(dd - (pd[k] - td[k]));
                float nr  = (k < 3) ? pv[k + 1] : p5;
                float nt2 = (k < 3) ? tv[k + 1] : t5;
                s[2] += fabsf(dd - (nr - nt2));
                float qd = qp[k] - qt[k];
                s[8] = fmaf(qd, qd, s[8]);
            }
            *(uint2*)&Iq[r * IQ_S + d * 4] =
                make_uint2(pk2(qp[0], qp[1]), pk2(qp[2], qp[3]));
            *(uint2*)&Iq[IQ_H + r * IQ_S + d * 4] =
                make_uint2(pk2(qt[0], qt[1]), pk2(qt[2], qt[3]));
        }
        // halo 0: rows 0..63, cols 32..47 (in-bounds for interior)
        {
            int h = threadIdx.x;
            int r = h >> 2, d = 8 + (h & 3);
            const float* prow = pb + (size_t)(r0 + r) * WDIM + (c0 + d * 4);
            const float* trow = tb + (size_t)(r0 + r) * WDIM + (c0 + d * 4);
            float4 a4 = *(const float4*)prow;
            float4 b4 = *(const float4*)trow;
            float qp[4] = {quant_u8f(a4.x), quant_u8f(a4.y), quant_u8f(a4.z), quant_u8f(a4.w)};
            float qt[4] = {quant_u8f(b4.x), quant_u8f(b4.y), quant_u8f(b4.z), quant_u8f(b4.w)};
            *(uint2*)&Iq[r * IQ_S + d * 4] =
                make_uint2(pk2(qp[0], qp[1]), pk2(qp[2], qp[3]));
            *(uint2*)&Iq[IQ_H + r * IQ_S + d * 4] =
                make_uint2(pk2(qt[0], qt[1]), pk2(qt[2], qt[3]));
        }
        // halo 1: rows 64..79, all 12 dword-groups (192 items)
        if (threadIdx.x < 192) {
            int h = threadIdx.x;
            int rq = h / 12;
            int r = 64 + rq, d = h - rq * 12;
            const float* prow = pb + (size_t)(r0 + r) * WDIM + (c0 + d * 4);
            const float* trow = tb + (size_t)(r0 + r) * WDIM + (c0 + d * 4);
            float4 a4 = *(const float4*)prow;
            float4 b4 = *(const float4*)trow;
            float qp[4] = {quant_u8f(a4.x), quant_u8f(a4.y), quant_u8f(a4.z), quant_u8f(a4.w)};
            float qt[4] = {quant_u8f(b4.x), quant_u8f(b4.y), quant_u8f(b4.z), quant_u8f(b4.w)};
            *(uint2*)&Iq[r * IQ_S + d * 4] =
                make_uint2(pk2(qp[0], qp[1]), pk2(qp[2], qp[3]));
            *(uint2*)&Iq[IQ_H + r * IQ_S + d * 4] =
                make_uint2(pk2(qt[0], qt[1]), pk2(qt[2], qt[3]));
        }
    } else {
        // edge tiles: same enumeration, guarded (core pixels always in-bounds;
        // only down-row, right-neighbor, and halo need guards)
#pragma unroll
        for (int i = 0; i < 2; ++i) {
            int item = threadIdx.x + i * 256;
            int r = item >> 3, d = item & 7;
            int gr = r0 + r, gc = c0 + d * 4;
            const float* prow = pb + (size_t)gr * WDIM + gc;
            const float* trow = tb + (size_t)gr * WDIM + gc;
            float4 a4 = *(const float4*)prow;
            float4 b4 = *(const float4*)trow;
            bool down = gr < (HDIM - 1);
            bool hasR = (gc + 4) < WDIM;
            float4 z4 = make_float4(0.f, 0.f, 0.f, 0.f);
            float4 ad = down ? *(const float4*)(prow + WDIM) : z4;
            float4 bd = down ? *(const float4*)(trow + WDIM) : z4;
            float p5 = hasR ? prow[4] : 0.0f;
            float t5 = hasR ? trow[4] : 0.0f;
            float pv[4] = {a4.x, a4.y, a4.z, a4.w};
            float tv[4] = {b4.x, b4.y, b4.z, b4.w};
            float pd[4] = {ad.x, ad.y, ad.z, ad.w};
            float td[4] = {bd.x, bd.y, bd.z, bd.w};
            float qp[4], qt[4];
#pragma unroll
            for (int k = 0; k < 4; ++k) { qp[k] = quant_u8f(pv[k]); qt[k] = quant_u8f(tv[k]); }
#pragma unroll
            for (int k = 0; k < 4; ++k) {
                float av = pv[k], bv = tv[k];
                float dd = av - bv;
                s[0] += fabsf(dd);
                s[3] += fmaxf(fabsf(av) - 1.0f, 0.0f);
                s[4] += av;  s[5] += bv;
                s[6] = fmaf(av, av, s[6]);
                s[7] = fmaf(bv, bv, s[7]);
                if (down) s[1] += fabsf(dd - (pd[k] - td[k]));
                float nr  = (k < 3) ? pv[k + 1] : p5;
                float nt2 = (k < 3) ? tv[k + 1] : t5;
                if (k < 3 || hasR) s[2] += fabsf(dd - (nr - nt2));
                float qd = qp[k] - qt[k];
                s[8] = fmaf(qd, qd, s[8]);
            }
            *(uint2*)&Iq[r * IQ_S + d * 4] =
                make_uint2(pk2(qp[0], qp[1]), pk2(qp[2], qp[3]));
            *(uint2*)&Iq[IQ_H + r * IQ_S + d * 4] =
                make_uint2(pk2(qt[0], qt[1]), pk2(qt[2], qt[3]));
        }
#pragma unroll
        for (int ph = 0; ph < 2; ++ph) {
            int r, d;
            bool active = true;
            if (ph == 0) { int h = threadIdx.x; r = h >> 2; d = 8 + (h & 3); }
            else {
                int h = threadIdx.x;
                active = h < 192;
                int rq = h / 12;
                r = 64 + rq; d = h - rq * 12;
            }
            if (active) {
                int gr = r0 + r, gc = c0 + d * 4;
                bool rowok = gr < HDIM;
                const float* prow = pb + (size_t)gr * WDIM + gc;
                const float* trow = tb + (size_t)gr * WDIM + gc;
                float qp[4], qt[4];
                if (rowok && (gc + 3) < WDIM) {
                    float4 a4 = *(const float4*)prow;
                    float4 b4 = *(const float4*)trow;
                    qp[0]=quant_u8f(a4.x); qp[1]=quant_u8f(a4.y); qp[2]=quant_u8f(a4.z); qp[3]=quant_u8f(a4.w);
                    qt[0]=quant_u8f(b4.x); qt[1]=quant_u8f(b4.y); qt[2]=quant_u8f(b4.z); qt[3]=quant_u8f(b4.w);
                } else {
#pragma unroll
                    for (int k = 0; k < 4; ++k) {
                        bool ok = rowok && (gc + k) < WDIM;
                        qp[k] = ok ? quant_u8f(prow[k]) : 0.0f;
                        qt[k] = ok ? quant_u8f(trow[k]) : 0.0f;
                    }
                }
                *(uint2*)&Iq[r * IQ_S + d * 4] =
                    make_uint2(pk2(qp[0], qp[1]), pk2(qp[2], qp[3]));
                *(uint2*)&Iq[IQ_H + r * IQ_S + d * 4] =
                    make_uint2(pk2(qt[0], qt[1]), pk2(qt[2], qt[3]));
            }
        }
    }
    __syncthreads();

    const int lane = threadIdx.x & 63;
    const int wid  = threadIdx.x >> 6;
    const int q    = lane >> 4;
    const int ml   = lane & 15;
    // shared Gaussian fragment: horizontal B-operand == vertical A-operand.
    // Loaded BEFORE the aliasing barrier -- Tg is dead after this.
    const half8 gfrag = *(const half8*)&Tg[ml * 32 + q * 8];
    const f32x4 zero4 = {0.f, 0.f, 0.f, 0.f};

    // ---- stage H part 1: preload A-fragments for this wave's positions ----
    // positions pos = wid, wid+4, wid+8 (wid 0,1 -> 3 positions; wid 2,3 -> 2)
    const int npos = (wid < 2) ? 3 : 2;
    half8 hap[3], hat[3];
#pragma unroll
    for (int i = 0; i < 3; ++i) {
        if (i < npos) {
            int pos = wid + i * 4;
            int rb = (pos >> 1) * 16;
            int cb = pos & 1;
            int base = (rb + ml) * IQ_S + cb * 16 + q * 8;
            hap[i] = *(const half8*)&Iq[base];
            hat[i] = *(const half8*)&Iq[IQ_H + base];
        }
    }
    __syncthreads();   // all Iq/Tg reads done -> HT may overwrite the union buffer

    // ---- stage H part 2: horizontal conv via MFMA; HT aliases Iq+Tg ----
#pragma unroll
    for (int i = 0; i < 3; ++i) {
        if (i < npos) {
            int pos = wid + i * 4;
            int rb = (pos >> 1) * 16;
            int cb = pos & 1;
            const half8 ap = hap[i];
            const half8 at = hat[i];
            f32x4 d0 = __builtin_amdgcn_mfma_f32_16x16x32_f16(ap,      gfrag, zero4, 0, 0, 0);
            f32x4 d1 = __builtin_amdgcn_mfma_f32_16x16x32_f16(at,      gfrag, zero4, 0, 0, 0);
            f32x4 d2 = __builtin_amdgcn_mfma_f32_16x16x32_f16(ap * ap, gfrag, zero4, 0, 0, 0);
            f32x4 d3 = __builtin_amdgcn_mfma_f32_16x16x32_f16(at * at, gfrag, zero4, 0, 0, 0);
            f32x4 d4 = __builtin_amdgcn_mfma_f32_16x16x32_f16(ap * at, gfrag, zero4, 0, 0, 0);
            // transposed write: HT[arr][col = cb*16+ml][row = rb + q*4 + 0..3]
            int hb = (cb * 16 + ml) * HT_R + rb + q * 4;
            *(uint2*)&Ubuf[0 * HT_A + hb] = make_uint2(pk2(d0[0], d0[1]), pk2(d0[2], d0[3]));
            *(uint2*)&Ubuf[1 * HT_A + hb] = make_uint2(pk2(d1[0], d1[1]), pk2(d1[2], d1[3]));
            *(uint2*)&Ubuf[2 * HT_A + hb] = make_uint2(pk2(d2[0], d2[1]), pk2(d2[2], d2[3]));
            *(uint2*)&Ubuf[3 * HT_A + hb] = make_uint2(pk2(d3[0], d3[1]), pk2(d3[2], d3[3]));
            *(uint2*)&Ubuf[4 * HT_A + hb] = make_uint2(pk2(d4[0], d4[1]), pk2(d4[2], d4[3]));
        }
    }
    __syncthreads();

    // ---- stage V: vertical conv via MFMA + SSIM map; 8 positions, 2/wave ----
    float ssum = 0.0f;
    const int th_ = min(TH, OUTW - r0);
    const int tw_ = min(TW, OUTW - c0);
    for (int vp = wid; vp < 8; vp += 4) {
        int rb2 = (vp >> 1) * 16;
        int cb2 = vp & 1;
        f32x4 acc[5];
#pragma unroll
        for (int arr = 0; arr < 5; ++arr) {
            const half8 bf = *(const half8*)&Ubuf[arr * HT_A +
                                                  (cb2 * 16 + ml) * HT_R + rb2 + q * 8];
            acc[arr] = __builtin_amdgcn_mfma_f32_16x16x32_f16(gfrag, bf, zero4, 0, 0, 0);
        }
        int col = cb2 * 16 + ml;
#pragma unroll
        for (int reg = 0; reg < 4; ++reg) {
            int row = rb2 + q * 4 + reg;
            if (interior || (row < th_ && col < tw_)) {
                float mu1 = acc[0][reg], mu2 = acc[1][reg];
                float vpp = acc[2][reg], vtt = acc[3][reg], vpt = acc[4][reg];
                float mu1s = mu1 * mu1, mu2s = mu2 * mu2, mu12 = mu1 * mu2;
                float sg1 = vpp - mu1s, sg2 = vtt - mu2s, sg12 = vpt - mu12;
                float num = (2.0f * mu12 + C1F) * (2.0f * sg12 + C2F);
                float den = (mu1s + mu2s + C1F) * (sg1 + sg2 + C2F);
                ssum += num * __builtin_amdgcn_rcpf(den);
            }
        }
    }

    // ---- block reduction of 10 partials; per-block stores ----
    float st10[10];
#pragma unroll
    for (int c = 0; c < 9; ++c) st10[c] = s[c];
    st10[9] = ssum;
#pragma unroll
    for (int c = 0; c < 10; ++c) {
        float v = st10[c];
        for (int off = 32; off > 0; off >>= 1) v += __shfl_down(v, off);
        st10[c] = v;
    }
    if (lane == 0) {
#pragma unroll
        for (int c = 0; c < 10; ++c) sred[wid][c] = st10[c];
    }
    __syncthreads();
    if (threadIdx.x < 10) {
        int c = threadIdx.x;
        int bid = ((b * 32) + blockIdx.y) * 64 + blockIdx.x;
        pr[c * NBLK + bid] = sred[0][c] + sred[1][c] + sred[2][c] + sred[3][c];
    }
}

// ---------------------------------------------------------------------------
// Final: ONE block. 40 segments of 2048 contiguous floats, coalesced float4
// reads, f64 shfl-reduce; thread 0 does the scalar combine.
// ---------------------------------------------------------------------------
__global__ __launch_bounds__(256) void amsr2_final(
        const float* __restrict__ pr, float* __restrict__ out)
{
    __shared__ double seg[40];
    int wid = threadIdx.x >> 6, lane = threadIdx.x & 63;
    for (int sidx = wid; sidx < 40; sidx += 4) {
        int c = sidx >> 2, b = sidx & 3;
        const float* base = pr + c * NBLK + b * 2048;
        float4 v[8];
#pragma unroll
        for (int it = 0; it < 8; ++it)
            v[it] = *(const float4*)(base + (it * 64 + lane) * 4);
        double acc = 0.0;
#pragma unroll
        for (int it = 0; it < 8; ++it)
            acc += (double)v[it].x + (double)v[it].y + (double)v[it].z + (double)v[it].w;
        for (int off = 32; off > 0; off >>= 1) acc += __shfl_down(acc, off);
        if (lane == 0) seg[sidx] = acc;
    }
    __syncthreads();
    if (threadIdx.x != 0) return;
    const double n = (double)NPIX;
    double sum0 = 0, sum1 = 0, sum2 = 0, sum3 = 0;
    for (int b = 0; b < 4; ++b) {
        sum0 += seg[0*4+b]; sum1 += seg[1*4+b]; sum2 += seg[2*4+b]; sum3 += seg[3*4+b];
    }
    double l1   = sum0 / (4.0 * n);
    double grad = sum1 / (4.0 * 2047.0 * 2048.0) + sum2 / (4.0 * 2048.0 * 2047.0);
    double energy = 0.0, dist = 0.0, psnr_sum = 0.0, ssim_sum = 0.0;
    for (int b = 0; b < 4; ++b) {
        double Sp  = seg[4*4+b],  St  = seg[5*4+b];
        double Spp = seg[6*4+b],  Stt = seg[7*4+b];
        double Su8 = seg[8*4+b],  Sss = seg[9*4+b];
        double pm = Sp / n, tm = St / n;
        double dm = pm - tm; energy += dm * dm;
        double vp = (Spp - n * pm * pm) / (n - 1.0);
        double vt = (Stt - n * tm * tm) / (n - 1.0);
        double ps = sqrt(fmax(vp, 0.0)), ts = sqrt(fmax(vt, 0.0));
        double dd = ps - ts; dist += dd * dd;
        double mse = Su8 / n;
        double psnr = (mse == 0.0) ? 100.0 : 10.0 * log10(65025.0 / fmax(mse, 1e-12));
        psnr_sum += psnr;
        ssim_sum += Sss / ((double)OUTW * (double)OUTW);
    }
    energy *= 0.25; dist *= 0.25;
    double range_pen = sum3 / (4.0 * n);
    double phys = energy + 0.5 * dist + 0.1 * range_pen;
    double ssim_mean = fmin(fmax(ssim_sum * 0.25, 0.0), 1.0);
    double total = l1 + 0.15 * grad + 0.05 * phys + 0.1 * (1.0 - ssim_mean);
    out[0] = (float)total;
    out[1] = (float)(psnr_sum * 0.25);
    out[2] = (float)ssim_mean;
}

extern "C" void kernel_launch(void* const* d_in, const int* in_sizes, int n_in,
                              void* d_out, int out_size, void* d_ws, size_t ws_size,
                              hipStream_t stream)
{
    (void)in_sizes; (void)n_in; (void)out_size; (void)ws_size;
    const float* pred = (const float*)d_in[0];
    const float* targ = (const float*)d_in[1];
    float* out = (float*)d_out;
    float* pr  = (float*)d_ws;            // 10 * 8192 floats of per-block partials

    GaussW gw;                            // host-side f64 Gaussian, cast to f32
    {
        double e[11], sm = 0.0;
        for (int i = 0; i < 11; ++i) {
            double d = (double)(i - 5);
            e[i] = exp(-(d * d) / 4.5);
            sm += e[i];
        }
        for (int i = 0; i < 11; ++i) gw.g[i] = (float)(e[i] / sm);
    }

    amsr2_fused<<<dim3(64, 32, 4), 256, 0, stream>>>(pred, targ, pr, gw);
    amsr2_final<<<1, 256, 0, stream>>>(pr, out);
}

// Round 4
// 174.378 us; speedup vs baseline: 1.0214x; 1.0214x over previous
//
#include <hip/hip_runtime.h>
#include <math.h>

#define HDIM 2048
#define WDIM 2048
#define NPIX (HDIM*WDIM)
#define OUTW 2038          /* valid conv output size: 2048-10 */

#define C1F 6.5025f        /* (0.01*255)^2 */
#define C2F 58.5225f       /* (0.03*255)^2 */

constexpr int TH   = 64, TW = 32;  // output tile
constexpr int IN_R = 80;           // input rows staged (5 MFMA row-blocks of 16)
constexpr int IQ_S = 72;           // f16 staging row stride (144 B)
constexpr int IQ_H = IN_R * IQ_S;  // 5760 f16 per image
constexpr int HT_R = 80;           // HT row stride: [arr][col][row]
constexpr int HT_A = 32 * HT_R;    // 2560 f16 per array
constexpr int NBLK = 8192;         // 64 x 32 x 4 blocks

struct GaussW { float g[11]; };

typedef _Float16 half8 __attribute__((ext_vector_type(8)));
typedef float    f32x4 __attribute__((ext_vector_type(4)));
typedef float    f32x2 __attribute__((ext_vector_type(2)));

// quant: bit-exact vs reference sequence. (clip(x)+1)*0.5 then *255 ==
// (clip(x)+1)*127.5 (the *0.5 is exact); trunc == floor for v >= 0.
// NOTE: must stay add-then-mul (two roundings) to match the reference --
// do NOT let this become fma.
__device__ __forceinline__ float quant_u8f(float x) {
    float c = __builtin_amdgcn_fmed3f(x, -1.0f, 1.0f);
    return truncf((c + 1.0f) * 127.5f);
}

// packed-pair quant: same scalar op sequence per element (med3/trunc are
// per-element; the add and mul pair into v_pk_add_f32 / v_pk_mul_f32).
__device__ __forceinline__ f32x2 quant2(f32x2 x) {
    f32x2 c = { __builtin_amdgcn_fmed3f(x.x, -1.0f, 1.0f),
                __builtin_amdgcn_fmed3f(x.y, -1.0f, 1.0f) };
    f32x2 v = (c + 1.0f) * 127.5f;     // pk_add then pk_mul: matches reference
    return { truncf(v.x), truncf(v.y) };
}

__device__ __forceinline__ unsigned pk2(float a, float b) {
    return __builtin_bit_cast(unsigned, __builtin_amdgcn_cvt_pkrtz(a, b));
}

// ---------------------------------------------------------------------------
// Fused kernel, MFMA edition (round 11: VALU-count cuts; layout unchanged).
//   VALU-bound per r1-r3 evidence (occupancy +22% -> time flat; dur tracks
//   per-wave VALU cycles). Cuts: dd-reuse for s1/s2, packed-f32 (VOP3P)
//   accumulators for non-abs channels, float2 SSIM map, 4-level xor-shuffle
//   reduction (ds_swizzle rides the idle LDS pipe).
// Channels: 0:l1 1:gxH 2:gyW 3:relu 4:sp 5:st 6:spp 7:stt 8:su8 9:ssim
// ---------------------------------------------------------------------------
__global__ __launch_bounds__(256, 6) void amsr2_fused(
        const float* __restrict__ pred, const float* __restrict__ targ,
        float* __restrict__ pr, GaussW gw)
{
    __shared__ alignas(16) _Float16 Ubuf[5 * HT_A];   // 12800 f16 = 25600 B
    __shared__ float sred[16][10];
    _Float16* Iq = Ubuf;                     // [0, 23040 B): 2 x 80 x 72 f16
    _Float16* Tg = Ubuf + 2 * IQ_H;          // [23040, 24064 B): 16 x 32 f16

    const int b  = blockIdx.z;
    const int r0 = blockIdx.y * TH;
    const int c0 = blockIdx.x * TW;
    const float* pb = pred + (size_t)b * NPIX;
    const float* tb = targ + (size_t)b * NPIX;
    const bool interior = (blockIdx.y < 31) && (blockIdx.x < 63);

    // ---- banded Gaussian table (threads 0..15; each owns its row) ----
    if (threadIdx.x < 16) {
        int n = threadIdx.x;
#pragma unroll
        for (int i = 0; i < 16; ++i) ((unsigned*)Tg)[n * 16 + i] = 0u;
#pragma unroll
        for (int j = 0; j < 11; ++j) Tg[n * 32 + n + j] = (_Float16)gw.g[j];
    }

    // abs-channels scalar (|x| folds into VOP3 modifiers); rest packed.
    float s0 = 0.f, s1 = 0.f, s2 = 0.f, s3 = 0.f, ssum = 0.f;
    f32x2 s4v = {0.f, 0.f}, s5v = {0.f, 0.f}, s6v = {0.f, 0.f},
          s7v = {0.f, 0.f}, s8v = {0.f, 0.f}, ssv = {0.f, 0.f};

    // ---- stage A: 80 rows x 48 cols staged; core(512) + halo(256+192) ----
    if (interior) {
        // core items: 64 rows x 8 dword-groups (cols 0..31) -- fully unguarded
#pragma unroll
        for (int i = 0; i < 2; ++i) {
            int item = threadIdx.x + i * 256;
            int r = item >> 3, d = item & 7;
            const float* prow = pb + (size_t)(r0 + r) * WDIM + (c0 + d * 4);
            const float* trow = tb + (size_t)(r0 + r) * WDIM + (c0 + d * 4);
            float4 a4 = *(const float4*)prow;
            float4 b4 = *(const float4*)trow;
            float4 ad = *(const float4*)(prow + WDIM);
            float4 bd = *(const float4*)(trow + WDIM);
            float p5 = prow[4], t5 = trow[4];

            f32x2 a01 = {a4.x, a4.y}, a23 = {a4.z, a4.w};
            f32x2 b01 = {b4.x, b4.y}, b23 = {b4.z, b4.w};
            f32x2 dd01 = a01 - b01, dd23 = a23 - b23;        // pk_sub
            float dd4 = p5 - t5;                             // dd of col+4
            f32x2 g01 = f32x2{ad.x, ad.y} - f32x2{bd.x, bd.y};  // down-row dd
            f32x2 g23 = f32x2{ad.z, ad.w} - f32x2{bd.z, bd.w};

            // l1
            s0 += fabsf(dd01.x); s0 += fabsf(dd01.y);
            s0 += fabsf(dd23.x); s0 += fabsf(dd23.y);
            // gxH: |dd - dd_down|
            s1 += fabsf(dd01.x - g01.x); s1 += fabsf(dd01.y - g01.y);
            s1 += fabsf(dd23.x - g23.x); s1 += fabsf(dd23.y - g23.y);
            // gyW: |dd_k - dd_{k+1}| (dd-reuse: right neighbor already computed)
            s2 += fabsf(dd01.x - dd01.y); s2 += fabsf(dd01.y - dd23.x);
            s2 += fabsf(dd23.x - dd23.y); s2 += fabsf(dd23.y - dd4);
            // range penalty
            s3 += fmaxf(fabsf(a4.x) - 1.0f, 0.0f);
            s3 += fmaxf(fabsf(a4.y) - 1.0f, 0.0f);
            s3 += fmaxf(fabsf(a4.z) - 1.0f, 0.0f);
            s3 += fmaxf(fabsf(a4.w) - 1.0f, 0.0f);
            // packed sums / sumsqs
            s4v += a01; s4v += a23;
            s5v += b01; s5v += b23;
            s6v += a01 * a01; s6v += a23 * a23;   // pk_fma
            s7v += b01 * b01; s7v += b23 * b23;
            // quant + u8 mse
            f32x2 qp01 = quant2(a01), qp23 = quant2(a23);
            f32x2 qt01 = quant2(b01), qt23 = quant2(b23);
            f32x2 qd01 = qp01 - qt01, qd23 = qp23 - qt23;
            s8v += qd01 * qd01; s8v += qd23 * qd23;

            *(uint2*)&Iq[r * IQ_S + d * 4] =
                make_uint2(pk2(qp01.x, qp01.y), pk2(qp23.x, qp23.y));
            *(uint2*)&Iq[IQ_H + r * IQ_S + d * 4] =
                make_uint2(pk2(qt01.x, qt01.y), pk2(qt23.x, qt23.y));
        }
        // halo 0: rows 0..63, cols 32..47 (in-bounds for interior)
        {
            int h = threadIdx.x;
            int r = h >> 2, d = 8 + (h & 3);
            const float* prow = pb + (size_t)(r0 + r) * WDIM + (c0 + d * 4);
            const float* trow = tb + (size_t)(r0 + r) * WDIM + (c0 + d * 4);
            float4 a4 = *(const float4*)prow;
            float4 b4 = *(const float4*)trow;
            f32x2 qp01 = quant2(f32x2{a4.x, a4.y}), qp23 = quant2(f32x2{a4.z, a4.w});
            f32x2 qt01 = quant2(f32x2{b4.x, b4.y}), qt23 = quant2(f32x2{b4.z, b4.w});
            *(uint2*)&Iq[r * IQ_S + d * 4] =
                make_uint2(pk2(qp01.x, qp01.y), pk2(qp23.x, qp23.y));
            *(uint2*)&Iq[IQ_H + r * IQ_S + d * 4] =
                make_uint2(pk2(qt01.x, qt01.y), pk2(qt23.x, qt23.y));
        }
        // halo 1: rows 64..79, all 12 dword-groups (192 items)
        if (threadIdx.x < 192) {
            int h = threadIdx.x;
            int rq = h / 12;
            int r = 64 + rq, d = h - rq * 12;
            const float* prow = pb + (size_t)(r0 + r) * WDIM + (c0 + d * 4);
            const float* trow = tb + (size_t)(r0 + r) * WDIM + (c0 + d * 4);
            float4 a4 = *(const float4*)prow;
            float4 b4 = *(const float4*)trow;
            f32x2 qp01 = quant2(f32x2{a4.x, a4.y}), qp23 = quant2(f32x2{a4.z, a4.w});
            f32x2 qt01 = quant2(f32x2{b4.x, b4.y}), qt23 = quant2(f32x2{b4.z, b4.w});
            *(uint2*)&Iq[r * IQ_S + d * 4] =
                make_uint2(pk2(qp01.x, qp01.y), pk2(qp23.x, qp23.y));
            *(uint2*)&Iq[IQ_H + r * IQ_S + d * 4] =
                make_uint2(pk2(qt01.x, qt01.y), pk2(qt23.x, qt23.y));
        }
    } else {
        // edge tiles: round-3 path, guarded; scalar adds into the same accums
#pragma unroll
        for (int i = 0; i < 2; ++i) {
            int item = threadIdx.x + i * 256;
            int r = item >> 3, d = item & 7;
            int gr = r0 + r, gc = c0 + d * 4;
            const float* prow = pb + (size_t)gr * WDIM + gc;
            const float* trow = tb + (size_t)gr * WDIM + gc;
            float4 a4 = *(const float4*)prow;
            float4 b4 = *(const float4*)trow;
            bool down = gr < (HDIM - 1);
            bool hasR = (gc + 4) < WDIM;
            float4 z4 = make_float4(0.f, 0.f, 0.f, 0.f);
            float4 ad = down ? *(const float4*)(prow + WDIM) : z4;
            float4 bd = down ? *(const float4*)(trow + WDIM) : z4;
            float p5 = hasR ? prow[4] : 0.0f;
            float t5 = hasR ? trow[4] : 0.0f;
            float pv[4] = {a4.x, a4.y, a4.z, a4.w};
            float tv[4] = {b4.x, b4.y, b4.z, b4.w};
            float pd[4] = {ad.x, ad.y, ad.z, ad.w};
            float td[4] = {bd.x, bd.y, bd.z, bd.w};
            float qp[4], qt[4];
#pragma unroll
            for (int k = 0; k < 4; ++k) { qp[k] = quant_u8f(pv[k]); qt[k] = quant_u8f(tv[k]); }
#pragma unroll
            for (int k = 0; k < 4; ++k) {
                float av = pv[k], bv = tv[k];
                float dd = av - bv;
                s0 += fabsf(dd);
                s3 += fmaxf(fabsf(av) - 1.0f, 0.0f);
                s4v.x += av;  s5v.x += bv;
                s6v.x = fmaf(av, av, s6v.x);
                s7v.x = fmaf(bv, bv, s7v.x);
                if (down) s1 += fabsf(dd - (pd[k] - td[k]));
                float nr  = (k < 3) ? pv[k + 1] : p5;
                float nt2 = (k < 3) ? tv[k + 1] : t5;
                if (k < 3 || hasR) s2 += fabsf(dd - (nr - nt2));
                float qd = qp[k] - qt[k];
                s8v.x = fmaf(qd, qd, s8v.x);
            }
            *(uint2*)&Iq[r * IQ_S + d * 4] =
                make_uint2(pk2(qp[0], qp[1]), pk2(qp[2], qp[3]));
            *(uint2*)&Iq[IQ_H + r * IQ_S + d * 4] =
                make_uint2(pk2(qt[0], qt[1]), pk2(qt[2], qt[3]));
        }
#pragma unroll
        for (int ph = 0; ph < 2; ++ph) {
            int r, d;
            bool active = true;
            if (ph == 0) { int h = threadIdx.x; r = h >> 2; d = 8 + (h & 3); }
            else {
                int h = threadIdx.x;
                active = h < 192;
                int rq = h / 12;
                r = 64 + rq; d = h - rq * 12;
            }
            if (active) {
                int gr = r0 + r, gc = c0 + d * 4;
                bool rowok = gr < HDIM;
                const float* prow = pb + (size_t)gr * WDIM + gc;
                const float* trow = tb + (size_t)gr * WDIM + gc;
                float qp[4], qt[4];
                if (rowok && (gc + 3) < WDIM) {
                    float4 a4 = *(const float4*)prow;
                    float4 b4 = *(const float4*)trow;
                    qp[0]=quant_u8f(a4.x); qp[1]=quant_u8f(a4.y); qp[2]=quant_u8f(a4.z); qp[3]=quant_u8f(a4.w);
                    qt[0]=quant_u8f(b4.x); qt[1]=quant_u8f(b4.y); qt[2]=quant_u8f(b4.z); qt[3]=quant_u8f(b4.w);
                } else {
#pragma unroll
                    for (int k = 0; k < 4; ++k) {
                        bool ok = rowok && (gc + k) < WDIM;
                        qp[k] = ok ? quant_u8f(prow[k]) : 0.0f;
                        qt[k] = ok ? quant_u8f(trow[k]) : 0.0f;
                    }
                }
                *(uint2*)&Iq[r * IQ_S + d * 4] =
                    make_uint2(pk2(qp[0], qp[1]), pk2(qp[2], qp[3]));
                *(uint2*)&Iq[IQ_H + r * IQ_S + d * 4] =
                    make_uint2(pk2(qt[0], qt[1]), pk2(qt[2], qt[3]));
            }
        }
    }
    __syncthreads();

    const int lane = threadIdx.x & 63;
    const int wid  = threadIdx.x >> 6;
    const int q    = lane >> 4;
    const int ml   = lane & 15;
    // shared Gaussian fragment: horizontal B-operand == vertical A-operand.
    // Loaded BEFORE the aliasing barrier -- Tg is dead after this.
    const half8 gfrag = *(const half8*)&Tg[ml * 32 + q * 8];
    const f32x4 zero4 = {0.f, 0.f, 0.f, 0.f};

    // ---- stage H part 1: preload A-fragments for this wave's positions ----
    const int npos = (wid < 2) ? 3 : 2;
    half8 hap[3], hat[3];
#pragma unroll
    for (int i = 0; i < 3; ++i) {
        if (i < npos) {
            int pos = wid + i * 4;
            int rb = (pos >> 1) * 16;
            int cb = pos & 1;
            int base = (rb + ml) * IQ_S + cb * 16 + q * 8;
            hap[i] = *(const half8*)&Iq[base];
            hat[i] = *(const half8*)&Iq[IQ_H + base];
        }
    }
    __syncthreads();   // all Iq/Tg reads done -> HT may overwrite the union buffer

    // ---- stage H part 2: horizontal conv via MFMA; HT aliases Iq+Tg ----
#pragma unroll
    for (int i = 0; i < 3; ++i) {
        if (i < npos) {
            int pos = wid + i * 4;
            int rb = (pos >> 1) * 16;
            int cb = pos & 1;
            const half8 ap = hap[i];
            const half8 at = hat[i];
            f32x4 d0 = __builtin_amdgcn_mfma_f32_16x16x32_f16(ap,      gfrag, zero4, 0, 0, 0);
            f32x4 d1 = __builtin_amdgcn_mfma_f32_16x16x32_f16(at,      gfrag, zero4, 0, 0, 0);
            f32x4 d2 = __builtin_amdgcn_mfma_f32_16x16x32_f16(ap * ap, gfrag, zero4, 0, 0, 0);
            f32x4 d3 = __builtin_amdgcn_mfma_f32_16x16x32_f16(at * at, gfrag, zero4, 0, 0, 0);
            f32x4 d4 = __builtin_amdgcn_mfma_f32_16x16x32_f16(ap * at, gfrag, zero4, 0, 0, 0);
            // transposed write: HT[arr][col = cb*16+ml][row = rb + q*4 + 0..3]
            int hb = (cb * 16 + ml) * HT_R + rb + q * 4;
            *(uint2*)&Ubuf[0 * HT_A + hb] = make_uint2(pk2(d0[0], d0[1]), pk2(d0[2], d0[3]));
            *(uint2*)&Ubuf[1 * HT_A + hb] = make_uint2(pk2(d1[0], d1[1]), pk2(d1[2], d1[3]));
            *(uint2*)&Ubuf[2 * HT_A + hb] = make_uint2(pk2(d2[0], d2[1]), pk2(d2[2], d2[3]));
            *(uint2*)&Ubuf[3 * HT_A + hb] = make_uint2(pk2(d3[0], d3[1]), pk2(d3[2], d3[3]));
            *(uint2*)&Ubuf[4 * HT_A + hb] = make_uint2(pk2(d4[0], d4[1]), pk2(d4[2], d4[3]));
        }
    }
    __syncthreads();

    // ---- stage V: vertical conv via MFMA + SSIM map; 8 positions, 2/wave ----
    const int th_ = min(TH, OUTW - r0);
    const int tw_ = min(TW, OUTW - c0);
    for (int vp = wid; vp < 8; vp += 4) {
        int rb2 = (vp >> 1) * 16;
        int cb2 = vp & 1;
        f32x4 acc[5];
#pragma unroll
        for (int arr = 0; arr < 5; ++arr) {
            const half8 bf = *(const half8*)&Ubuf[arr * HT_A +
                                                  (cb2 * 16 + ml) * HT_R + rb2 + q * 8];
            acc[arr] = __builtin_amdgcn_mfma_f32_16x16x32_f16(gfrag, bf, zero4, 0, 0, 0);
        }
        if (interior) {
            // packed SSIM map: reg pairs {0,1},{2,3}
#pragma unroll
            for (int pp = 0; pp < 2; ++pp) {
                f32x2 mu1 = {acc[0][2*pp], acc[0][2*pp+1]};
                f32x2 mu2 = {acc[1][2*pp], acc[1][2*pp+1]};
                f32x2 vpp = {acc[2][2*pp], acc[2][2*pp+1]};
                f32x2 vtt = {acc[3][2*pp], acc[3][2*pp+1]};
                f32x2 vpt = {acc[4][2*pp], acc[4][2*pp+1]};
                f32x2 mu12 = mu1 * mu2, mu1s = mu1 * mu1, mu2s = mu2 * mu2;
                f32x2 sg12 = vpt - mu12, sg1 = vpp - mu1s, sg2 = vtt - mu2s;
                f32x2 num = (2.0f * mu12 + C1F) * (2.0f * sg12 + C2F);
                f32x2 den = (mu1s + mu2s + C1F) * (sg1 + sg2 + C2F);
                f32x2 rp = { __builtin_amdgcn_rcpf(den.x),
                             __builtin_amdgcn_rcpf(den.y) };
                ssv += num * rp;
            }
        } else {
            int col = cb2 * 16 + ml;
#pragma unroll
            for (int reg = 0; reg < 4; ++reg) {
                int row = rb2 + q * 4 + reg;
                if (row < th_ && col < tw_) {
                    float mu1 = acc[0][reg], mu2 = acc[1][reg];
                    float vpp = acc[2][reg], vtt = acc[3][reg], vpt = acc[4][reg];
                    float mu1s = mu1 * mu1, mu2s = mu2 * mu2, mu12 = mu1 * mu2;
                    float sg1 = vpp - mu1s, sg2 = vtt - mu2s, sg12 = vpt - mu12;
                    float num = (2.0f * mu12 + C1F) * (2.0f * sg12 + C2F);
                    float den = (mu1s + mu2s + C1F) * (sg1 + sg2 + C2F);
                    ssum += num * __builtin_amdgcn_rcpf(den);
                }
            }
        }
    }

    // ---- block reduction: 4-level xor tree within 16-lane groups ----
    float st10[10];
    st10[0] = s0; st10[1] = s1; st10[2] = s2; st10[3] = s3;
    st10[4] = s4v.x + s4v.y; st10[5] = s5v.x + s5v.y;
    st10[6] = s6v.x + s6v.y; st10[7] = s7v.x + s7v.y;
    st10[8] = s8v.x + s8v.y; st10[9] = ssum + ssv.x + ssv.y;
#pragma unroll
    for (int c = 0; c < 10; ++c) {
        float v = st10[c];
        v += __shfl_xor(v, 8);
        v += __shfl_xor(v, 4);
        v += __shfl_xor(v, 2);
        v += __shfl_xor(v, 1);
        st10[c] = v;
    }
    if ((lane & 15) == 0) {
        int g = wid * 4 + (lane >> 4);
#pragma unroll
        for (int c = 0; c < 10; ++c) sred[g][c] = st10[c];
    }
    __syncthreads();
    if (threadIdx.x < 10) {
        int c = threadIdx.x;
        float t = 0.0f;
#pragma unroll
        for (int g = 0; g < 16; ++g) t += sred[g][c];
        int bid = ((b * 32) + blockIdx.y) * 64 + blockIdx.x;
        pr[c * NBLK + bid] = t;
    }
}

// ---------------------------------------------------------------------------
// Final: ONE block. 40 segments of 2048 contiguous floats, coalesced float4
// reads, f64 shfl-reduce; thread 0 does the scalar combine.
// ---------------------------------------------------------------------------
__global__ __launch_bounds__(256) void amsr2_final(
        const float* __restrict__ pr, float* __restrict__ out)
{
    __shared__ double seg[40];
    int wid = threadIdx.x >> 6, lane = threadIdx.x & 63;
    for (int sidx = wid; sidx < 40; sidx += 4) {
        int c = sidx >> 2, b = sidx & 3;
        const float* base = pr + c * NBLK + b * 2048;
        float4 v[8];
#pragma unroll
        for (int it = 0; it < 8; ++it)
            v[it] = *(const float4*)(base + (it * 64 + lane) * 4);
        double acc = 0.0;
#pragma unroll
        for (int it = 0; it < 8; ++it)
            acc += (double)v[it].x + (double)v[it].y + (double)v[it].z + (double)v[it].w;
        for (int off = 32; off > 0; off >>= 1) acc += __shfl_down(acc, off);
        if (lane == 0) seg[sidx] = acc;
    }
    __syncthreads();
    if (threadIdx.x != 0) return;
    const double n = (double)NPIX;
    double sum0 = 0, sum1 = 0, sum2 = 0, sum3 = 0;
    for (int b = 0; b < 4; ++b) {
        sum0 += seg[0*4+b]; sum1 += seg[1*4+b]; sum2 += seg[2*4+b]; sum3 += seg[3*4+b];
    }
    double l1   = sum0 / (4.0 * n);
    double grad = sum1 / (4.0 * 2047.0 * 2048.0) + sum2 / (4.0 * 2048.0 * 2047.0);
    double energy = 0.0, dist = 0.0, psnr_sum = 0.0, ssim_sum = 0.0;
    for (int b = 0; b < 4; ++b) {
        double Sp  = seg[4*4+b],  St  = seg[5*4+b];
        double Spp = seg[6*4+b],  Stt = seg[7*4+b];
        double Su8 = seg[8*4+b],  Sss = seg[9*4+b];
        double pm = Sp / n, tm = St / n;
        double dm = pm - tm; energy += dm * dm;
        double vp = (Spp - n * pm * pm) / (n - 1.0);
        double vt = (Stt - n * tm * tm) / (n - 1.0);
        double ps = sqrt(fmax(vp, 0.0)), ts = sqrt(fmax(vt, 0.0));
        double dd = ps - ts; dist += dd * dd;
        double mse = Su8 / n;
        double psnr = (mse == 0.0) ? 100.0 : 10.0 * log10(65025.0 / fmax(mse, 1e-12));
        psnr_sum += psnr;
        ssim_sum += Sss / ((double)OUTW * (double)OUTW);
    }
    energy *= 0.25; dist *= 0.25;
    double range_pen = sum3 / (4.0 * n);
    double phys = energy + 0.5 * dist + 0.1 * range_pen;
    double ssim_mean = fmin(fmax(ssim_sum * 0.25, 0.0), 1.0);
    double total = l1 + 0.15 * grad + 0.05 * phys + 0.1 * (1.0 - ssim_mean);
    out[0] = (float)total;
    out[1] = (float)(psnr_sum * 0.25);
    out[2] = (float)ssim_mean;
}

extern "C" void kernel_launch(void* const* d_in, const int* in_sizes, int n_in,
                              void* d_out, int out_size, void* d_ws, size_t ws_size,
                              hipStream_t stream)
{
    (void)in_sizes; (void)n_in; (void)out_size; (void)ws_size;
    const float* pred = (const float*)d_in[0];
    const float* targ = (const float*)d_in[1];
    float* out = (float*)d_out;
    float* pr  = (float*)d_ws;            // 10 * 8192 floats of per-block partials

    GaussW gw;                            // host-side f64 Gaussian, cast to f32
    {
        double e[11], sm = 0.0;
        for (int i = 0; i < 11; ++i) {
            double d = (double)(i - 5);
            e[i] = exp(-(d * d) / 4.5);
            sm += e[i];
        }
        for (int i = 0; i < 11; ++i) gw.g[i] = (float)(e[i] / sm);
    }

    amsr2_fused<<<dim3(64, 32, 4), 256, 0, stream>>>(pred, targ, pr, gw);
    amsr2_final<<<1, 256, 0, stream>>>(pr, out);
}